// Round 15
// baseline (203.382 us; speedup 1.0000x reference)
//
#include <hip/hip_runtime.h>

// ---------------------------------------------------------------------------
// Types / helpers
// ---------------------------------------------------------------------------
typedef __attribute__((ext_vector_type(8))) short bf16x8;   // 8 bf16 = 4 VGPR
typedef __attribute__((ext_vector_type(4))) short bf16x4;   // 8 bytes
typedef __attribute__((ext_vector_type(4))) float f32x4;    // MFMA acc

static __device__ __forceinline__ short f2bf(float f) {      // RNE
    union { float f; unsigned u; } v; v.f = f;
    unsigned r = v.u + 0x7fffu + ((v.u >> 16) & 1u);
    return (short)(r >> 16);
}

// async global->LDS, 16B per lane; lds dest MUST be base + lane*16 (m97/m104)
static __device__ __forceinline__ void async_copy16(const short* g, short* l) {
    __builtin_amdgcn_global_load_lds((const __attribute__((address_space(1))) void*)g,
                                     (__attribute__((address_space(3))) void*)l,
                                     16, 0, 0);
}

#if defined(__has_builtin)
#  if __has_builtin(__builtin_amdgcn_mfma_f32_16x16x16bf16_1k)
#    define HAVE_MFMA16 1
#  endif
#endif
#ifndef HAVE_MFMA16
#  define HAVE_MFMA16 0
#endif

#define HEADS 16
#define DHEAD 64
#define NSEQ  2048
#define DIM   1024
#define BATCH 2
#define ROWS  (BATCH * NSEQ)          // 4096
#define NQKV  (3 * HEADS * DHEAD)     // 3072

// ---------------------------------------------------------------------------
// Prep megakernel — one dispatch, roles by block range:
//   [0,768):      w_qkv [1024][3072] -> wqkvT [3072][1024]  (64x64 tiles)
//   [768,1024):   w_out [1024][1024] -> woutT [1024][1024]  (64x64 tiles)
//   [1024,5120):  rmsnorm row (blk-1024)
// ---------------------------------------------------------------------------
__global__ __launch_bounds__(256) void prep_kernel(const float* __restrict__ x,
                                                   const float* __restrict__ gamma,
                                                   const float* __restrict__ w_qkv,
                                                   const float* __restrict__ w_out,
                                                   short* __restrict__ xn,
                                                   short* __restrict__ wqkvT,
                                                   short* __restrict__ woutT) {
    const int blk = blockIdx.x;
    const int t = threadIdx.x;
    __shared__ float tile[64][65];
    __shared__ float part[4];

    if (blk < 1024) {
        // ---- transpose+cast role (64x64 tile) ----
        const float* in;  short* out;  int C, bx, by;
        if (blk < 768) { in = w_qkv; out = wqkvT; C = NQKV; bx = blk % 48; by = blk / 48; }
        else           { in = w_out; out = woutT; C = DIM;  bx = (blk - 768) & 15; by = (blk - 768) >> 4; }
        const int gx = bx * 64, gy = by * 64;
        const int lc4 = (t & 15) * 4;          // load col 0..60
        const int lr  = t >> 4;                // load row 0..15 (x4 passes)
#pragma unroll
        for (int p = 0; p < 4; ++p) {
            const float4 v = *(const float4*)&in[(size_t)(gy + p * 16 + lr) * C + gx + lc4];
            tile[p * 16 + lr][lc4 + 0] = v.x;
            tile[p * 16 + lr][lc4 + 1] = v.y;
            tile[p * 16 + lr][lc4 + 2] = v.z;
            tile[p * 16 + lr][lc4 + 3] = v.w;
        }
        __syncthreads();
        const int oc  = t >> 2;                // output row 0..63 (input col)
        const int or4 = (t & 3) * 16;          // 16 output elems per thread
#pragma unroll
        for (int j = 0; j < 4; ++j) {
            bf16x4 w;
#pragma unroll
            for (int r = 0; r < 4; ++r) w[r] = f2bf(tile[or4 + j * 4 + r][oc]);
            *(bf16x4*)&out[(size_t)(gx + oc) * DIM + gy + or4 + j * 4] = w;
        }
    } else {
        // ---- rmsnorm role ----
        const int row = blk - 1024;
        const float4 v = ((const float4*)(x + (size_t)row * DIM))[t];
        float s = v.x * v.x + v.y * v.y + v.z * v.z + v.w * v.w;
#pragma unroll
        for (int off = 32; off > 0; off >>= 1) s += __shfl_down(s, off, 64);
        if ((t & 63) == 0) part[t >> 6] = s;
        __syncthreads();
        const float tot = part[0] + part[1] + part[2] + part[3];
        const float scale = 32.0f / fmaxf(sqrtf(tot), 1e-12f);   // sqrt(1024)=32
        const float4 g = ((const float4*)gamma)[t];
        bf16x4 o;
        o[0] = f2bf(v.x * scale * g.x);
        o[1] = f2bf(v.y * scale * g.y);
        o[2] = f2bf(v.z * scale * g.z);
        o[3] = f2bf(v.w * scale * g.w);
        *(bf16x4*)(xn + (size_t)row * DIM + t * 4) = o;
    }
}

// ---------------------------------------------------------------------------
// GEMM: C[M x N] = A[M x K] * Bt[N x K]^T, bf16 in, fp32 acc.  BK=32 (m97).
// MODE 0: scatter q/k (q scaled d^-0.5); V written transposed (b64 stores).
// MODE 1: fp32 row-major output (direct).
// ---------------------------------------------------------------------------
template <int MODE, int MT, int NT, int WM, int WN>
__global__ __launch_bounds__(256) void gemm_bt(const short* __restrict__ A,
                                               const short* __restrict__ Bt,
                                               void* __restrict__ Cout,
                                               short* __restrict__ vtOut,
                                               int K, int N) {
    constexpr int TM = WM * MT * 16;
    constexpr int TN = WN * NT * 16;
    __shared__ alignas(16) short lds_a[TM * 32];   // unpadded: global_load_lds contract
    __shared__ alignas(16) short lds_b[TN * 32];
    const int tid = threadIdx.x;
    const int lane = tid & 63, wid = tid >> 6;
    const int quad = lane >> 4, l16 = lane & 15;
    const int wm = wid / WN, wn = wid % WN;
    const int mb = blockIdx.y * TM, nb = blockIdx.x * TN;

    f32x4 acc[MT][NT];
#pragma unroll
    for (int i = 0; i < MT; ++i)
#pragma unroll
        for (int j = 0; j < NT; ++j) acc[i][j] = (f32x4){0.f, 0.f, 0.f, 0.f};

    const int lr = lane >> 2;
    const int lc = (lane & 3) * 8;

    for (int kb = 0; kb < K; kb += 32) {
        __syncthreads();
#pragma unroll
        for (int c = 0; c < TM / 64; ++c) {
            const int row = c * 64 + wid * 16 + lr;
            async_copy16(&A[(size_t)(mb + row) * K + kb + lc], &lds_a[row * 32 + lc]);
        }
#pragma unroll
        for (int c = 0; c < TN / 64; ++c) {
            const int row = c * 64 + wid * 16 + lr;
            async_copy16(&Bt[(size_t)(nb + row) * K + kb + lc], &lds_b[row * 32 + lc]);
        }
        __syncthreads();
        bf16x8 af[MT], bfr[NT];
#pragma unroll
        for (int mt = 0; mt < MT; ++mt)
            af[mt] = *(const bf16x8*)&lds_a[(wm * MT * 16 + mt * 16 + l16) * 32 + quad * 8];
#pragma unroll
        for (int nt = 0; nt < NT; ++nt)
            bfr[nt] = *(const bf16x8*)&lds_b[(wn * NT * 16 + nt * 16 + l16) * 32 + quad * 8];
#pragma unroll
        for (int mt = 0; mt < MT; ++mt)
#pragma unroll
            for (int nt = 0; nt < NT; ++nt)
                acc[mt][nt] = __builtin_amdgcn_mfma_f32_16x16x32_bf16(af[mt], bfr[nt],
                                                                      acc[mt][nt], 0, 0, 0);
    }

#pragma unroll
    for (int mt = 0; mt < MT; ++mt) {
#pragma unroll
        for (int nt = 0; nt < NT; ++nt) {
            const int grow0 = mb + wm * MT * 16 + mt * 16 + quad * 4;
            const int gcol  = nb + wn * NT * 16 + nt * 16 + l16;
            if (MODE == 0) {
                const int s3 = gcol >> 10, rem = gcol & 1023;
                const int hh = rem >> 6, dd = rem & 63;
                const int bb = grow0 >> 11, npos0 = grow0 & 2047;
                if (s3 == 2) {
                    bf16x4 vw;
#pragma unroll
                    for (int r = 0; r < 4; ++r) vw[r] = f2bf(acc[mt][nt][r]);
                    *(bf16x4*)&vtOut[((size_t)(bb * 16 + hh) * 64 + dd) * 2048 + npos0] = vw;
                } else {
                    const float sc = (s3 == 0) ? 0.125f : 1.0f;   // q * d^-0.5
#pragma unroll
                    for (int r = 0; r < 4; ++r)
                        ((short*)Cout)[(size_t)((s3 * 32 + bb * 16 + hh) * 2048 + npos0 + r) * 64 +
                                       dd] = f2bf(acc[mt][nt][r] * sc);
                }
            } else {
#pragma unroll
                for (int r = 0; r < 4; ++r)
                    ((float*)Cout)[(size_t)(grow0 + r) * N + gcol] = acc[mt][nt][r];
            }
        }
    }
}

// ---------------------------------------------------------------------------
// Causal flash attention v4: query-split block + double-buffered LDS K/V.
// PV now consumes P DIRECTLY from registers via mfma_f32_16x16x16_bf16:
// the K=16 B-operand layout (n=l16, k=quad*4+i) is exactly the S C-layout
// (col=l16=query, row=quad*4+r=key) — no LDS P round-trip, no pbuf.
// V^T A-fragments are b64 LDS reads at (m&1)*16 + quad*4 within the slab.
// Fallback (no builtin): round-12 LDS round-trip path.
// ---------------------------------------------------------------------------
__global__ __launch_bounds__(256, 3) void attn_kernel(const short* __restrict__ qg,
                                                      const short* __restrict__ kg,
                                                      const short* __restrict__ vtg,
                                                      short* __restrict__ og) {
    const int tid = threadIdx.x;
    const int wid = tid >> 6, lane = tid & 63;
    const int quad = lane >> 4, l16 = lane & 15;
    const int blk = blockIdx.x;                 // 0..511
    const int qt = 15 - (blk >> 5);             // heavy query-tiles first
    const int bh = blk & 31;
    const size_t base = (size_t)bh * (NSEQ * DHEAD);
    const int bb = bh >> 4, hh = bh & 15;
    const int qbase = qt * 128 + wid * 32;      // this wave's first query
    const int ntiles = 2 * qt + 2;              // 64-key tiles (even)

    __shared__ alignas(16) short kA[2][2048], kB[2][2048];   // 8 KB each
    __shared__ alignas(16) short vA[2][2048], vB[2][2048];   // 8 KB each
#if !HAVE_MFMA16
    __shared__ alignas(16) short pbuf[4][32 * 72];           // fallback P transform
    short* const pb = pbuf[wid];
#endif

    const int sr = tid >> 2;          // 0..63 (row)
    const int sc = (tid & 3) * 8;     // 0..24 (col, shorts)
    auto stage = [&](int t, short (&KB_)[2][2048], short (&VB_)[2][2048]) {
        const int kb = t * 64;
        async_copy16(&kg[base + (size_t)(kb + sr) * 64 + sc],      &KB_[0][sr * 32 + sc]);
        async_copy16(&kg[base + (size_t)(kb + sr) * 64 + 32 + sc], &KB_[1][sr * 32 + sc]);
        async_copy16(&vtg[base + (size_t)sr * 2048 + kb + sc],      &VB_[0][sr * 32 + sc]);
        async_copy16(&vtg[base + (size_t)sr * 2048 + kb + 32 + sc], &VB_[1][sr * 32 + sc]);
    };

    bf16x8 qf[2][2];
#pragma unroll
    for (int qn = 0; qn < 2; ++qn)
#pragma unroll
        for (int kh = 0; kh < 2; ++kh)
            qf[qn][kh] = *(const bf16x8*)&qg[base + (size_t)(qbase + qn * 16 + l16) * DHEAD +
                                            kh * 32 + quad * 8];

    float li[2] = {0.f, 0.f};
    f32x4 accO[2][4];
#pragma unroll
    for (int qn = 0; qn < 2; ++qn)
#pragma unroll
        for (int nc = 0; nc < 4; ++nc) accO[qn][nc] = (f32x4){0.f, 0.f, 0.f, 0.f};

    auto tile_step = [&](const short (&KB_)[2][2048], const short (&VB_)[2][2048], int t) {
        const int kb = t * 64;
        // ---- S^T = K Q^T : 16 K=32 MFMAs (K frags from LDS) ----
        f32x4 sf[2][4];
#pragma unroll
        for (int m = 0; m < 4; ++m) {
            const bf16x8 kf0 = *(const bf16x8*)&KB_[0][(m * 16 + l16) * 32 + quad * 8];
            const bf16x8 kf1 = *(const bf16x8*)&KB_[1][(m * 16 + l16) * 32 + quad * 8];
#pragma unroll
            for (int qn = 0; qn < 2; ++qn) {
                f32x4 z = (f32x4){0.f, 0.f, 0.f, 0.f};
                z = __builtin_amdgcn_mfma_f32_16x16x32_bf16(kf0, qf[qn][0], z, 0, 0, 0);
                sf[qn][m] = __builtin_amdgcn_mfma_f32_16x16x32_bf16(kf1, qf[qn][1], z, 0, 0, 0);
            }
        }
        // ---- causal mask (diagonal tiles only; wave-uniform branch) ----
        if (kb + 64 > qbase) {
#pragma unroll
            for (int qn = 0; qn < 2; ++qn) {
                const int myq = qbase + qn * 16 + l16;
#pragma unroll
                for (int m = 0; m < 4; ++m)
#pragma unroll
                    for (int r = 0; r < 4; ++r)
                        if (kb + m * 16 + quad * 4 + r > myq) sf[qn][m][r] = -3.0e38f;
            }
        }
#if HAVE_MFMA16
        // ---- p = exp(s) packed in registers = ready-made K=16 B-fragment ----
        bf16x4 pw[2][4];
#pragma unroll
        for (int qn = 0; qn < 2; ++qn) {
            float rs = 0.f;
#pragma unroll
            for (int m = 0; m < 4; ++m) {
#pragma unroll
                for (int r = 0; r < 4; ++r) {
                    const float p = __expf(sf[qn][m][r]);
                    rs += p;
                    pw[qn][m][r] = f2bf(p);
                }
            }
            li[qn] += rs;
        }
        // ---- O^T += V^T P : 32 K=16 MFMAs, P direct from registers ----
#pragma unroll
        for (int nc = 0; nc < 4; ++nc) {
#pragma unroll
            for (int m = 0; m < 4; ++m) {
                const bf16x4 va = *(const bf16x4*)&VB_[m >> 1][(nc * 16 + l16) * 32 +
                                                              (m & 1) * 16 + quad * 4];
#pragma unroll
                for (int qn = 0; qn < 2; ++qn)
                    accO[qn][nc] = __builtin_amdgcn_mfma_f32_16x16x16bf16_1k(va, pw[qn][m],
                                                                            accO[qn][nc],
                                                                            0, 0, 0);
            }
        }
#else
        // ---- fallback: LDS P round-trip (round-12 path) ----
#pragma unroll
        for (int qn = 0; qn < 2; ++qn) {
            float rs = 0.f;
#pragma unroll
            for (int m = 0; m < 4; ++m) {
                bf16x4 pwv;
#pragma unroll
                for (int r = 0; r < 4; ++r) {
                    const float p = __expf(sf[qn][m][r]);
                    rs += p;
                    pwv[r] = f2bf(p);
                }
                *(bf16x4*)&pb[(qn * 16 + l16) * 72 + m * 16 + quad * 4] = pwv;
            }
            li[qn] += rs;
        }
        bf16x8 pf[2][2];
#pragma unroll
        for (int qn = 0; qn < 2; ++qn)
#pragma unroll
            for (int ks = 0; ks < 2; ++ks)
                pf[qn][ks] = *(const bf16x8*)&pb[(qn * 16 + l16) * 72 + ks * 32 + quad * 8];
#pragma unroll
        for (int nc = 0; nc < 4; ++nc) {
            const bf16x8 vf0 = *(const bf16x8*)&VB_[0][(nc * 16 + l16) * 32 + quad * 8];
            const bf16x8 vf1 = *(const bf16x8*)&VB_[1][(nc * 16 + l16) * 32 + quad * 8];
#pragma unroll
            for (int qn = 0; qn < 2; ++qn) {
                accO[qn][nc] = __builtin_amdgcn_mfma_f32_16x16x32_bf16(vf0, pf[qn][0],
                                                                      accO[qn][nc], 0, 0, 0);
                accO[qn][nc] = __builtin_amdgcn_mfma_f32_16x16x32_bf16(vf1, pf[qn][1],
                                                                      accO[qn][nc], 0, 0, 0);
            }
        }
#endif
    };

    stage(0, kA, vA);
    __syncthreads();
    for (int t = 0; t < ntiles; t += 2) {
        stage(t + 1, kB, vB);
        tile_step(kA, vA, t);
        __syncthreads();
        if (t + 2 < ntiles) stage(t + 2, kA, vA);
        tile_step(kB, vB, t + 1);
        __syncthreads();
    }

#pragma unroll
    for (int qn = 0; qn < 2; ++qn) {
        li[qn] += __shfl_xor(li[qn], 16, 64);
        li[qn] += __shfl_xor(li[qn], 32, 64);
        const float inv = 1.0f / li[qn];
        const int npos = qbase + qn * 16 + l16;
#pragma unroll
        for (int nc = 0; nc < 4; ++nc) {
            bf16x4 ow;
#pragma unroll
            for (int r = 0; r < 4; ++r) ow[r] = f2bf(accO[qn][nc][r] * inv);
            *(bf16x4*)&og[(size_t)(bb * 2048 + npos) * 1024 + hh * 64 + nc * 16 + quad * 4] = ow;
        }
    }
}

// ---------------------------------------------------------------------------
// Launch  (4 dispatches: prep, gemm<0>, attn, gemm<1>)
// ---------------------------------------------------------------------------
extern "C" void kernel_launch(void* const* d_in, const int* in_sizes, int n_in,
                              void* d_out, int out_size, void* d_ws, size_t ws_size,
                              hipStream_t stream) {
    const float* x     = (const float*)d_in[0];
    const float* gamma = (const float*)d_in[1];
    const float* w_qkv = (const float*)d_in[2];
    const float* w_out = (const float*)d_in[3];
    float* out = (float*)d_out;
    char* ws = (char*)d_ws;

    short* xn     = (short*)(ws);                    //  8 MB
    short* wqkvT  = (short*)(ws + 8388608);          //  6 MB
    short* woutT  = (short*)(ws + 14680064);         //  2 MB
    short* q      = (short*)(ws + 16777216);         //  8 MB: [32][2048][64]
    short* k      = q + 32 * 2048 * 64;              //  8 MB: [32][2048][64]
    short* vt     = k + 32 * 2048 * 64;              //  8 MB: [32][64][2048] (written by gemm<0>)
    short* attn   = (short*)(ws + 41943040);         //  8 MB

    // prep: 768 (wqkv T) + 256 (wout T) + 4096 (rmsnorm) = 5120 blocks
    prep_kernel<<<5120, 256, 0, stream>>>(x, gamma, w_qkv, w_out, xn, wqkvT, woutT);
    // 128x128 tile, BK=32: 24x32 = 768 blocks (3/CU)
    gemm_bt<0, 4, 4, 2, 2><<<dim3(NQKV / 128, ROWS / 128), 256, 0, stream>>>(xn, wqkvT, q, vt,
                                                                             DIM, NQKV);
    // 512 blocks: (bh, 128-query tile), heavy qt first; 4 waves query-split
    attn_kernel<<<512, 256, 0, stream>>>(q, k, vt, attn);
    // 128x64 tile direct fp32: 16x32 = 512 blocks (2/CU)
    gemm_bt<1, 2, 4, 4, 1><<<dim3(DIM / 64, ROWS / 128), 256, 0, stream>>>(attn, woutT, out,
                                                                           nullptr, DIM, DIM);
}

// Round 16
// 185.210 us; speedup vs baseline: 1.0981x; 1.0981x over previous
//
#include <hip/hip_runtime.h>

// ---------------------------------------------------------------------------
// Types / helpers
// ---------------------------------------------------------------------------
typedef __attribute__((ext_vector_type(8))) short bf16x8;   // 8 bf16 = 4 VGPR
typedef __attribute__((ext_vector_type(4))) short bf16x4;   // 8 bytes
typedef __attribute__((ext_vector_type(4))) float f32x4;    // MFMA acc

static __device__ __forceinline__ short f2bf(float f) {      // RNE
    union { float f; unsigned u; } v; v.f = f;
    unsigned r = v.u + 0x7fffu + ((v.u >> 16) & 1u);
    return (short)(r >> 16);
}

// async global->LDS, 16B per lane; lds dest MUST be base + lane*16 (m97/m104)
static __device__ __forceinline__ void async_copy16(const short* g, short* l) {
    __builtin_amdgcn_global_load_lds((const __attribute__((address_space(1))) void*)g,
                                     (__attribute__((address_space(3))) void*)l,
                                     16, 0, 0);
}

#define HEADS 16
#define DHEAD 64
#define NSEQ  2048
#define DIM   1024
#define BATCH 2
#define ROWS  (BATCH * NSEQ)          // 4096
#define NQKV  (3 * HEADS * DHEAD)     // 3072

// ---------------------------------------------------------------------------
// Prep megakernel — one dispatch, roles by block range:
//   [0,768):      w_qkv [1024][3072] -> wqkvT [3072][1024]  (64x64 tiles)
//   [768,1024):   w_out [1024][1024] -> woutT [1024][1024]  (64x64 tiles)
//   [1024,5120):  rmsnorm row (blk-1024)
// ---------------------------------------------------------------------------
__global__ __launch_bounds__(256) void prep_kernel(const float* __restrict__ x,
                                                   const float* __restrict__ gamma,
                                                   const float* __restrict__ w_qkv,
                                                   const float* __restrict__ w_out,
                                                   short* __restrict__ xn,
                                                   short* __restrict__ wqkvT,
                                                   short* __restrict__ woutT) {
    const int blk = blockIdx.x;
    const int t = threadIdx.x;
    __shared__ float tile[64][65];
    __shared__ float part[4];

    if (blk < 1024) {
        // ---- transpose+cast role (64x64 tile) ----
        const float* in;  short* out;  int C, bx, by;
        if (blk < 768) { in = w_qkv; out = wqkvT; C = NQKV; bx = blk % 48; by = blk / 48; }
        else           { in = w_out; out = woutT; C = DIM;  bx = (blk - 768) & 15; by = (blk - 768) >> 4; }
        const int gx = bx * 64, gy = by * 64;
        const int lc4 = (t & 15) * 4;          // load col 0..60
        const int lr  = t >> 4;                // load row 0..15 (x4 passes)
#pragma unroll
        for (int p = 0; p < 4; ++p) {
            const float4 v = *(const float4*)&in[(size_t)(gy + p * 16 + lr) * C + gx + lc4];
            tile[p * 16 + lr][lc4 + 0] = v.x;
            tile[p * 16 + lr][lc4 + 1] = v.y;
            tile[p * 16 + lr][lc4 + 2] = v.z;
            tile[p * 16 + lr][lc4 + 3] = v.w;
        }
        __syncthreads();
        const int oc  = t >> 2;                // output row 0..63 (input col)
        const int or4 = (t & 3) * 16;          // 16 output elems per thread
#pragma unroll
        for (int j = 0; j < 4; ++j) {
            bf16x4 w;
#pragma unroll
            for (int r = 0; r < 4; ++r) w[r] = f2bf(tile[or4 + j * 4 + r][oc]);
            *(bf16x4*)&out[(size_t)(gx + oc) * DIM + gy + or4 + j * 4] = w;
        }
    } else {
        // ---- rmsnorm role ----
        const int row = blk - 1024;
        const float4 v = ((const float4*)(x + (size_t)row * DIM))[t];
        float s = v.x * v.x + v.y * v.y + v.z * v.z + v.w * v.w;
#pragma unroll
        for (int off = 32; off > 0; off >>= 1) s += __shfl_down(s, off, 64);
        if ((t & 63) == 0) part[t >> 6] = s;
        __syncthreads();
        const float tot = part[0] + part[1] + part[2] + part[3];
        const float scale = 32.0f / fmaxf(sqrtf(tot), 1e-12f);   // sqrt(1024)=32
        const float4 g = ((const float4*)gamma)[t];
        bf16x4 o;
        o[0] = f2bf(v.x * scale * g.x);
        o[1] = f2bf(v.y * scale * g.y);
        o[2] = f2bf(v.z * scale * g.z);
        o[3] = f2bf(v.w * scale * g.w);
        *(bf16x4*)(xn + (size_t)row * DIM + t * 4) = o;
    }
}

// ---------------------------------------------------------------------------
// GEMM: C[M x N] = A[M x K] * Bt[N x K]^T, bf16 in, fp32 acc.  BK=32 (m97).
// SWZ: XCD chunk swizzle — dispatch-linear id lin maps XCD (lin&7) to a
// 6x16 tile chunk so per-XCD L2 demand ~5.5 MB (vs 8.75 MB stripes).
// MODE 0: scatter q/k (q scaled d^-0.5); V written transposed (b64 stores).
// MODE 1: fp32 row-major output (direct).
// ---------------------------------------------------------------------------
template <int MODE, int MT, int NT, int WM, int WN, bool SWZ>
__global__ __launch_bounds__(256) void gemm_bt(const short* __restrict__ A,
                                               const short* __restrict__ Bt,
                                               void* __restrict__ Cout,
                                               short* __restrict__ vtOut,
                                               int K, int N) {
    constexpr int TM = WM * MT * 16;
    constexpr int TN = WN * NT * 16;
    __shared__ alignas(16) short lds_a[TM * 32];   // unpadded: global_load_lds contract
    __shared__ alignas(16) short lds_b[TN * 32];
    const int tid = threadIdx.x;
    const int lane = tid & 63, wid = tid >> 6;
    const int quad = lane >> 4, l16 = lane & 15;
    const int wm = wid / WN, wn = wid % WN;
    int bx = blockIdx.x, by = blockIdx.y;
    if (SWZ) {
        // grid must be 24 x 32; lin follows dispatch order (x fast)
        const int lin = by * 24 + bx;
        const int xcd = lin & 7, s = lin >> 3;        // s in 0..95
        bx = (xcd & 3) * 6 + s % 6;                   // nb chunk: 6 tiles
        by = (xcd >> 2) * 16 + s / 6;                 // mb chunk: 16 tiles
    }
    const int mb = by * TM, nb = bx * TN;

    f32x4 acc[MT][NT];
#pragma unroll
    for (int i = 0; i < MT; ++i)
#pragma unroll
        for (int j = 0; j < NT; ++j) acc[i][j] = (f32x4){0.f, 0.f, 0.f, 0.f};

    // staging: per call, wave w covers 16 rows; lane l -> row +l/4, col (l&3)*8
    const int lr = lane >> 2;
    const int lc = (lane & 3) * 8;

    for (int kb = 0; kb < K; kb += 32) {
        __syncthreads();   // all waves done reading previous tile
#pragma unroll
        for (int c = 0; c < TM / 64; ++c) {
            const int row = c * 64 + wid * 16 + lr;
            async_copy16(&A[(size_t)(mb + row) * K + kb + lc], &lds_a[row * 32 + lc]);
        }
#pragma unroll
        for (int c = 0; c < TN / 64; ++c) {
            const int row = c * 64 + wid * 16 + lr;
            async_copy16(&Bt[(size_t)(nb + row) * K + kb + lc], &lds_b[row * 32 + lc]);
        }
        __syncthreads();   // compiler drains vmcnt before barrier
        bf16x8 af[MT], bfr[NT];
#pragma unroll
        for (int mt = 0; mt < MT; ++mt)
            af[mt] = *(const bf16x8*)&lds_a[(wm * MT * 16 + mt * 16 + l16) * 32 + quad * 8];
#pragma unroll
        for (int nt = 0; nt < NT; ++nt)
            bfr[nt] = *(const bf16x8*)&lds_b[(wn * NT * 16 + nt * 16 + l16) * 32 + quad * 8];
#pragma unroll
        for (int mt = 0; mt < MT; ++mt)
#pragma unroll
            for (int nt = 0; nt < NT; ++nt)
                acc[mt][nt] = __builtin_amdgcn_mfma_f32_16x16x32_bf16(af[mt], bfr[nt],
                                                                      acc[mt][nt], 0, 0, 0);
    }

#pragma unroll
    for (int mt = 0; mt < MT; ++mt) {
#pragma unroll
        for (int nt = 0; nt < NT; ++nt) {
            const int grow0 = mb + wm * MT * 16 + mt * 16 + quad * 4;   // r-run base row
            const int gcol  = nb + wn * NT * 16 + nt * 16 + l16;
            if (MODE == 0) {
                const int s3 = gcol >> 10, rem = gcol & 1023;   // s3 wave-uniform per nt
                const int hh = rem >> 6, dd = rem & 63;
                const int bb = grow0 >> 11, npos0 = grow0 & 2047;
                if (s3 == 2) {
                    // vt[bh][d][n]: r-run contiguous in n -> one b64 store
                    bf16x4 vw;
#pragma unroll
                    for (int r = 0; r < 4; ++r) vw[r] = f2bf(acc[mt][nt][r]);
                    *(bf16x4*)&vtOut[((size_t)(bb * 16 + hh) * 64 + dd) * 2048 + npos0] = vw;
                } else {
                    const float sc = (s3 == 0) ? 0.125f : 1.0f;   // q * d^-0.5
#pragma unroll
                    for (int r = 0; r < 4; ++r)
                        ((short*)Cout)[(size_t)((s3 * 32 + bb * 16 + hh) * 2048 + npos0 + r) * 64 +
                                       dd] = f2bf(acc[mt][nt][r] * sc);
                }
            } else {
#pragma unroll
                for (int r = 0; r < 4; ++r)
                    ((float*)Cout)[(size_t)(grow0 + r) * N + gcol] = acc[mt][nt][r];
            }
        }
    }
}

// ---------------------------------------------------------------------------
// Causal flash attention v3: query-split block + double-buffered LDS K/V.
// (exact round-12/14 version — best measured; edits to this loop regress)
// ---------------------------------------------------------------------------
__global__ __launch_bounds__(256, 3) void attn_kernel(const short* __restrict__ qg,
                                                      const short* __restrict__ kg,
                                                      const short* __restrict__ vtg,
                                                      short* __restrict__ og) {
    const int tid = threadIdx.x;
    const int wid = tid >> 6, lane = tid & 63;
    const int quad = lane >> 4, l16 = lane & 15;
    const int blk = blockIdx.x;                 // 0..511
    const int qt = 15 - (blk >> 5);             // heavy query-tiles first
    const int bh = blk & 31;
    const size_t base = (size_t)bh * (NSEQ * DHEAD);
    const int bb = bh >> 4, hh = bh & 15;
    const int qbase = qt * 128 + wid * 32;      // this wave's first query
    const int ntiles = 2 * qt + 2;              // 64-key tiles (even)

    __shared__ alignas(16) short kA[2][2048], kB[2][2048];   // 8 KB each
    __shared__ alignas(16) short vA[2][2048], vB[2][2048];   // 8 KB each
    __shared__ alignas(16) short pbuf[4][32 * 72];           // wave-private P (18.4 KB)
    short* const pb = pbuf[wid];

    const int sr = tid >> 2;          // 0..63 (row)
    const int sc = (tid & 3) * 8;     // 0..24 (col, shorts)
    auto stage = [&](int t, short (&KB_)[2][2048], short (&VB_)[2][2048]) {
        const int kb = t * 64;
        async_copy16(&kg[base + (size_t)(kb + sr) * 64 + sc],      &KB_[0][sr * 32 + sc]);
        async_copy16(&kg[base + (size_t)(kb + sr) * 64 + 32 + sc], &KB_[1][sr * 32 + sc]);
        async_copy16(&vtg[base + (size_t)sr * 2048 + kb + sc],      &VB_[0][sr * 32 + sc]);
        async_copy16(&vtg[base + (size_t)sr * 2048 + kb + 32 + sc], &VB_[1][sr * 32 + sc]);
    };

    bf16x8 qf[2][2];
#pragma unroll
    for (int qn = 0; qn < 2; ++qn)
#pragma unroll
        for (int kh = 0; kh < 2; ++kh)
            qf[qn][kh] = *(const bf16x8*)&qg[base + (size_t)(qbase + qn * 16 + l16) * DHEAD +
                                            kh * 32 + quad * 8];

    float li[2] = {0.f, 0.f};
    f32x4 accO[2][4];
#pragma unroll
    for (int qn = 0; qn < 2; ++qn)
#pragma unroll
        for (int nc = 0; nc < 4; ++nc) accO[qn][nc] = (f32x4){0.f, 0.f, 0.f, 0.f};

    auto tile_step = [&](const short (&KB_)[2][2048], const short (&VB_)[2][2048], int t) {
        const int kb = t * 64;
        f32x4 sf[2][4];
#pragma unroll
        for (int m = 0; m < 4; ++m) {
            const bf16x8 kf0 = *(const bf16x8*)&KB_[0][(m * 16 + l16) * 32 + quad * 8];
            const bf16x8 kf1 = *(const bf16x8*)&KB_[1][(m * 16 + l16) * 32 + quad * 8];
#pragma unroll
            for (int qn = 0; qn < 2; ++qn) {
                f32x4 z = (f32x4){0.f, 0.f, 0.f, 0.f};
                z = __builtin_amdgcn_mfma_f32_16x16x32_bf16(kf0, qf[qn][0], z, 0, 0, 0);
                sf[qn][m] = __builtin_amdgcn_mfma_f32_16x16x32_bf16(kf1, qf[qn][1], z, 0, 0, 0);
            }
        }
        if (kb + 64 > qbase) {
#pragma unroll
            for (int qn = 0; qn < 2; ++qn) {
                const int myq = qbase + qn * 16 + l16;
#pragma unroll
                for (int m = 0; m < 4; ++m)
#pragma unroll
                    for (int r = 0; r < 4; ++r)
                        if (kb + m * 16 + quad * 4 + r > myq) sf[qn][m][r] = -3.0e38f;
            }
        }
#pragma unroll
        for (int qn = 0; qn < 2; ++qn) {
            float rs = 0.f;
#pragma unroll
            for (int m = 0; m < 4; ++m) {
                bf16x4 pw;
#pragma unroll
                for (int r = 0; r < 4; ++r) {
                    const float p = __expf(sf[qn][m][r]);
                    rs += p;
                    pw[r] = f2bf(p);
                }
                *(bf16x4*)&pb[(qn * 16 + l16) * 72 + m * 16 + quad * 4] = pw;
            }
            li[qn] += rs;
        }
        bf16x8 pf[2][2];
#pragma unroll
        for (int qn = 0; qn < 2; ++qn)
#pragma unroll
            for (int ks = 0; ks < 2; ++ks)
                pf[qn][ks] = *(const bf16x8*)&pb[(qn * 16 + l16) * 72 + ks * 32 + quad * 8];
#pragma unroll
        for (int nc = 0; nc < 4; ++nc) {
            const bf16x8 vf0 = *(const bf16x8*)&VB_[0][(nc * 16 + l16) * 32 + quad * 8];
            const bf16x8 vf1 = *(const bf16x8*)&VB_[1][(nc * 16 + l16) * 32 + quad * 8];
#pragma unroll
            for (int qn = 0; qn < 2; ++qn) {
                accO[qn][nc] = __builtin_amdgcn_mfma_f32_16x16x32_bf16(vf0, pf[qn][0],
                                                                      accO[qn][nc], 0, 0, 0);
                accO[qn][nc] = __builtin_amdgcn_mfma_f32_16x16x32_bf16(vf1, pf[qn][1],
                                                                      accO[qn][nc], 0, 0, 0);
            }
        }
    };

    stage(0, kA, vA);
    __syncthreads();
    for (int t = 0; t < ntiles; t += 2) {
        stage(t + 1, kB, vB);
        tile_step(kA, vA, t);
        __syncthreads();
        if (t + 2 < ntiles) stage(t + 2, kA, vA);
        tile_step(kB, vB, t + 1);
        __syncthreads();
    }

#pragma unroll
    for (int qn = 0; qn < 2; ++qn) {
        li[qn] += __shfl_xor(li[qn], 16, 64);
        li[qn] += __shfl_xor(li[qn], 32, 64);
        const float inv = 1.0f / li[qn];
        const int npos = qbase + qn * 16 + l16;
#pragma unroll
        for (int nc = 0; nc < 4; ++nc) {
            bf16x4 ow;
#pragma unroll
            for (int r = 0; r < 4; ++r) ow[r] = f2bf(accO[qn][nc][r] * inv);
            *(bf16x4*)&og[(size_t)(bb * 2048 + npos) * 1024 + hh * 64 + nc * 16 + quad * 4] = ow;
        }
    }
}

// ---------------------------------------------------------------------------
// Launch  (4 dispatches: prep, gemm<0>, attn, gemm<1>)
// ---------------------------------------------------------------------------
extern "C" void kernel_launch(void* const* d_in, const int* in_sizes, int n_in,
                              void* d_out, int out_size, void* d_ws, size_t ws_size,
                              hipStream_t stream) {
    const float* x     = (const float*)d_in[0];
    const float* gamma = (const float*)d_in[1];
    const float* w_qkv = (const float*)d_in[2];
    const float* w_out = (const float*)d_in[3];
    float* out = (float*)d_out;
    char* ws = (char*)d_ws;

    short* xn     = (short*)(ws);                    //  8 MB
    short* wqkvT  = (short*)(ws + 8388608);          //  6 MB
    short* woutT  = (short*)(ws + 14680064);         //  2 MB
    short* q      = (short*)(ws + 16777216);         //  8 MB: [32][2048][64]
    short* k      = q + 32 * 2048 * 64;              //  8 MB: [32][2048][64]
    short* vt     = k + 32 * 2048 * 64;              //  8 MB: [32][64][2048] (written by gemm<0>)
    short* attn   = (short*)(ws + 41943040);         //  8 MB

    // prep: 768 (wqkv T) + 256 (wout T) + 4096 (rmsnorm) = 5120 blocks
    prep_kernel<<<5120, 256, 0, stream>>>(x, gamma, w_qkv, w_out, xn, wqkvT, woutT);
    // 128x128 tile, BK=32: 24x32 = 768 blocks (3/CU), XCD chunk swizzle
    gemm_bt<0, 4, 4, 2, 2, true><<<dim3(NQKV / 128, ROWS / 128), 256, 0, stream>>>(
        xn, wqkvT, q, vt, DIM, NQKV);
    // 512 blocks: (bh, 128-query tile), heavy qt first; 4 waves query-split
    attn_kernel<<<512, 256, 0, stream>>>(q, k, vt, attn);
    // 128x64 tile direct fp32: 16x32 = 512 blocks (2/CU)
    gemm_bt<1, 2, 4, 4, 1, false><<<dim3(DIM / 64, ROWS / 128), 256, 0, stream>>>(
        attn, woutT, out, nullptr, DIM, DIM);
}

// Round 17
// 184.797 us; speedup vs baseline: 1.1006x; 1.0022x over previous
//
#include <hip/hip_runtime.h>

// ---------------------------------------------------------------------------
// Types / helpers
// ---------------------------------------------------------------------------
typedef __attribute__((ext_vector_type(8))) short bf16x8;   // 8 bf16 = 4 VGPR
typedef __attribute__((ext_vector_type(4))) short bf16x4;   // 8 bytes
typedef __attribute__((ext_vector_type(4))) float f32x4;    // MFMA acc

static __device__ __forceinline__ short f2bf(float f) {      // RNE
    union { float f; unsigned u; } v; v.f = f;
    unsigned r = v.u + 0x7fffu + ((v.u >> 16) & 1u);
    return (short)(r >> 16);
}

// async global->LDS, 16B per lane; lds dest MUST be base + lane*16 (m97/m104)
static __device__ __forceinline__ void async_copy16(const short* g, short* l) {
    __builtin_amdgcn_global_load_lds((const __attribute__((address_space(1))) void*)g,
                                     (__attribute__((address_space(3))) void*)l,
                                     16, 0, 0);
}

#define HEADS 16
#define DHEAD 64
#define NSEQ  2048
#define DIM   1024
#define BATCH 2
#define ROWS  (BATCH * NSEQ)          // 4096
#define NQKV  (3 * HEADS * DHEAD)     // 3072

// ---------------------------------------------------------------------------
// Prep megakernel — one dispatch, roles by block range:
//   [0,768):      w_qkv [1024][3072] -> wqkvT [3072][1024]  (64x64 tiles)
//   [768,1024):   w_out [1024][1024] -> woutT [1024][1024]  (64x64 tiles)
//   [1024,5120):  rmsnorm row (blk-1024)
// ---------------------------------------------------------------------------
__global__ __launch_bounds__(256) void prep_kernel(const float* __restrict__ x,
                                                   const float* __restrict__ gamma,
                                                   const float* __restrict__ w_qkv,
                                                   const float* __restrict__ w_out,
                                                   short* __restrict__ xn,
                                                   short* __restrict__ wqkvT,
                                                   short* __restrict__ woutT) {
    const int blk = blockIdx.x;
    const int t = threadIdx.x;
    __shared__ float tile[64][65];
    __shared__ float part[4];

    if (blk < 1024) {
        // ---- transpose+cast role (64x64 tile) ----
        const float* in;  short* out;  int C, bx, by;
        if (blk < 768) { in = w_qkv; out = wqkvT; C = NQKV; bx = blk % 48; by = blk / 48; }
        else           { in = w_out; out = woutT; C = DIM;  bx = (blk - 768) & 15; by = (blk - 768) >> 4; }
        const int gx = bx * 64, gy = by * 64;
        const int lc4 = (t & 15) * 4;          // load col 0..60
        const int lr  = t >> 4;                // load row 0..15 (x4 passes)
#pragma unroll
        for (int p = 0; p < 4; ++p) {
            const float4 v = *(const float4*)&in[(size_t)(gy + p * 16 + lr) * C + gx + lc4];
            tile[p * 16 + lr][lc4 + 0] = v.x;
            tile[p * 16 + lr][lc4 + 1] = v.y;
            tile[p * 16 + lr][lc4 + 2] = v.z;
            tile[p * 16 + lr][lc4 + 3] = v.w;
        }
        __syncthreads();
        const int oc  = t >> 2;                // output row 0..63 (input col)
        const int or4 = (t & 3) * 16;          // 16 output elems per thread
#pragma unroll
        for (int j = 0; j < 4; ++j) {
            bf16x4 w;
#pragma unroll
            for (int r = 0; r < 4; ++r) w[r] = f2bf(tile[or4 + j * 4 + r][oc]);
            *(bf16x4*)&out[(size_t)(gx + oc) * DIM + gy + or4 + j * 4] = w;
        }
    } else {
        // ---- rmsnorm role ----
        const int row = blk - 1024;
        const float4 v = ((const float4*)(x + (size_t)row * DIM))[t];
        float s = v.x * v.x + v.y * v.y + v.z * v.z + v.w * v.w;
#pragma unroll
        for (int off = 32; off > 0; off >>= 1) s += __shfl_down(s, off, 64);
        if ((t & 63) == 0) part[t >> 6] = s;
        __syncthreads();
        const float tot = part[0] + part[1] + part[2] + part[3];
        const float scale = 32.0f / fmaxf(sqrtf(tot), 1e-12f);   // sqrt(1024)=32
        const float4 g = ((const float4*)gamma)[t];
        bf16x4 o;
        o[0] = f2bf(v.x * scale * g.x);
        o[1] = f2bf(v.y * scale * g.y);
        o[2] = f2bf(v.z * scale * g.z);
        o[3] = f2bf(v.w * scale * g.w);
        *(bf16x4*)(xn + (size_t)row * DIM + t * 4) = o;
    }
}

// ---------------------------------------------------------------------------
// GEMM: C[M x N] = A[M x K] * Bt[N x K]^T, bf16 in, fp32 acc.  BK=32 (m97).
// Tile = (WM*MT*16) x (WN*NT*16); 4 waves arranged WM x WN;
// global_load_lds width-16 staging into unpadded row-major 32-col LDS tiles.
// MODE 0: scatter q/k into [s][b*h][n][d] bf16 (q scaled d^-0.5);
//         V written TRANSPOSED to vtOut [b*h][d][n] via b64 stores.
// MODE 1: fp32 row-major output (direct).
// ---------------------------------------------------------------------------
template <int MODE, int MT, int NT, int WM, int WN>
__global__ __launch_bounds__(256) void gemm_bt(const short* __restrict__ A,
                                               const short* __restrict__ Bt,
                                               void* __restrict__ Cout,
                                               short* __restrict__ vtOut,
                                               int K, int N) {
    constexpr int TM = WM * MT * 16;
    constexpr int TN = WN * NT * 16;
    __shared__ alignas(16) short lds_a[TM * 32];   // unpadded: global_load_lds contract
    __shared__ alignas(16) short lds_b[TN * 32];
    const int tid = threadIdx.x;
    const int lane = tid & 63, wid = tid >> 6;
    const int quad = lane >> 4, l16 = lane & 15;
    const int wm = wid / WN, wn = wid % WN;
    const int mb = blockIdx.y * TM, nb = blockIdx.x * TN;

    f32x4 acc[MT][NT];
#pragma unroll
    for (int i = 0; i < MT; ++i)
#pragma unroll
        for (int j = 0; j < NT; ++j) acc[i][j] = (f32x4){0.f, 0.f, 0.f, 0.f};

    // staging: per call, wave w covers 16 rows; lane l -> row +l/4, col (l&3)*8
    const int lr = lane >> 2;
    const int lc = (lane & 3) * 8;

    for (int kb = 0; kb < K; kb += 32) {
        __syncthreads();   // all waves done reading previous tile
#pragma unroll
        for (int c = 0; c < TM / 64; ++c) {
            const int row = c * 64 + wid * 16 + lr;
            async_copy16(&A[(size_t)(mb + row) * K + kb + lc], &lds_a[row * 32 + lc]);
        }
#pragma unroll
        for (int c = 0; c < TN / 64; ++c) {
            const int row = c * 64 + wid * 16 + lr;
            async_copy16(&Bt[(size_t)(nb + row) * K + kb + lc], &lds_b[row * 32 + lc]);
        }
        __syncthreads();   // compiler drains vmcnt before barrier
        bf16x8 af[MT], bfr[NT];
#pragma unroll
        for (int mt = 0; mt < MT; ++mt)
            af[mt] = *(const bf16x8*)&lds_a[(wm * MT * 16 + mt * 16 + l16) * 32 + quad * 8];
#pragma unroll
        for (int nt = 0; nt < NT; ++nt)
            bfr[nt] = *(const bf16x8*)&lds_b[(wn * NT * 16 + nt * 16 + l16) * 32 + quad * 8];
#pragma unroll
        for (int mt = 0; mt < MT; ++mt)
#pragma unroll
            for (int nt = 0; nt < NT; ++nt)
                acc[mt][nt] = __builtin_amdgcn_mfma_f32_16x16x32_bf16(af[mt], bfr[nt],
                                                                      acc[mt][nt], 0, 0, 0);
    }

#pragma unroll
    for (int mt = 0; mt < MT; ++mt) {
#pragma unroll
        for (int nt = 0; nt < NT; ++nt) {
            const int grow0 = mb + wm * MT * 16 + mt * 16 + quad * 4;   // r-run base row
            const int gcol  = nb + wn * NT * 16 + nt * 16 + l16;
            if (MODE == 0) {
                const int s3 = gcol >> 10, rem = gcol & 1023;   // s3 wave-uniform per nt
                const int hh = rem >> 6, dd = rem & 63;
                const int bb = grow0 >> 11, npos0 = grow0 & 2047;
                if (s3 == 2) {
                    // vt[bh][d][n]: r-run contiguous in n -> one b64 store
                    bf16x4 vw;
#pragma unroll
                    for (int r = 0; r < 4; ++r) vw[r] = f2bf(acc[mt][nt][r]);
                    *(bf16x4*)&vtOut[((size_t)(bb * 16 + hh) * 64 + dd) * 2048 + npos0] = vw;
                } else {
                    const float sc = (s3 == 0) ? 0.125f : 1.0f;   // q * d^-0.5
#pragma unroll
                    for (int r = 0; r < 4; ++r)
                        ((short*)Cout)[(size_t)((s3 * 32 + bb * 16 + hh) * 2048 + npos0 + r) * 64 +
                                       dd] = f2bf(acc[mt][nt][r] * sc);
                }
            } else {
#pragma unroll
                for (int r = 0; r < 4; ++r)
                    ((float*)Cout)[(size_t)(grow0 + r) * N + gcol] = acc[mt][nt][r];
            }
        }
    }
}

// ---------------------------------------------------------------------------
// Causal flash attention v3: query-split block + double-buffered LDS K/V.
// (round-12/14 version — best measured; edits to this loop regress)
// ---------------------------------------------------------------------------
__global__ __launch_bounds__(256, 3) void attn_kernel(const short* __restrict__ qg,
                                                      const short* __restrict__ kg,
                                                      const short* __restrict__ vtg,
                                                      short* __restrict__ og) {
    const int tid = threadIdx.x;
    const int wid = tid >> 6, lane = tid & 63;
    const int quad = lane >> 4, l16 = lane & 15;
    const int blk = blockIdx.x;                 // 0..511
    const int qt = 15 - (blk >> 5);             // heavy query-tiles first
    const int bh = blk & 31;
    const size_t base = (size_t)bh * (NSEQ * DHEAD);
    const int bb = bh >> 4, hh = bh & 15;
    const int qbase = qt * 128 + wid * 32;      // this wave's first query
    const int ntiles = 2 * qt + 2;              // 64-key tiles (even)

    __shared__ alignas(16) short kA[2][2048], kB[2][2048];   // 8 KB each
    __shared__ alignas(16) short vA[2][2048], vB[2][2048];   // 8 KB each
    __shared__ alignas(16) short pbuf[4][32 * 72];           // wave-private P (18.4 KB)
    short* const pb = pbuf[wid];

    const int sr = tid >> 2;          // 0..63 (row)
    const int sc = (tid & 3) * 8;     // 0..24 (col, shorts)
    auto stage = [&](int t, short (&KB_)[2][2048], short (&VB_)[2][2048]) {
        const int kb = t * 64;
        async_copy16(&kg[base + (size_t)(kb + sr) * 64 + sc],      &KB_[0][sr * 32 + sc]);
        async_copy16(&kg[base + (size_t)(kb + sr) * 64 + 32 + sc], &KB_[1][sr * 32 + sc]);
        async_copy16(&vtg[base + (size_t)sr * 2048 + kb + sc],      &VB_[0][sr * 32 + sc]);
        async_copy16(&vtg[base + (size_t)sr * 2048 + kb + 32 + sc], &VB_[1][sr * 32 + sc]);
    };

    bf16x8 qf[2][2];
#pragma unroll
    for (int qn = 0; qn < 2; ++qn)
#pragma unroll
        for (int kh = 0; kh < 2; ++kh)
            qf[qn][kh] = *(const bf16x8*)&qg[base + (size_t)(qbase + qn * 16 + l16) * DHEAD +
                                            kh * 32 + quad * 8];

    float li[2] = {0.f, 0.f};
    f32x4 accO[2][4];
#pragma unroll
    for (int qn = 0; qn < 2; ++qn)
#pragma unroll
        for (int nc = 0; nc < 4; ++nc) accO[qn][nc] = (f32x4){0.f, 0.f, 0.f, 0.f};

    auto tile_step = [&](const short (&KB_)[2][2048], const short (&VB_)[2][2048], int t) {
        const int kb = t * 64;
        f32x4 sf[2][4];
#pragma unroll
        for (int m = 0; m < 4; ++m) {
            const bf16x8 kf0 = *(const bf16x8*)&KB_[0][(m * 16 + l16) * 32 + quad * 8];
            const bf16x8 kf1 = *(const bf16x8*)&KB_[1][(m * 16 + l16) * 32 + quad * 8];
#pragma unroll
            for (int qn = 0; qn < 2; ++qn) {
                f32x4 z = (f32x4){0.f, 0.f, 0.f, 0.f};
                z = __builtin_amdgcn_mfma_f32_16x16x32_bf16(kf0, qf[qn][0], z, 0, 0, 0);
                sf[qn][m] = __builtin_amdgcn_mfma_f32_16x16x32_bf16(kf1, qf[qn][1], z, 0, 0, 0);
            }
        }
        if (kb + 64 > qbase) {
#pragma unroll
            for (int qn = 0; qn < 2; ++qn) {
                const int myq = qbase + qn * 16 + l16;
#pragma unroll
                for (int m = 0; m < 4; ++m)
#pragma unroll
                    for (int r = 0; r < 4; ++r)
                        if (kb + m * 16 + quad * 4 + r > myq) sf[qn][m][r] = -3.0e38f;
            }
        }
#pragma unroll
        for (int qn = 0; qn < 2; ++qn) {
            float rs = 0.f;
#pragma unroll
            for (int m = 0; m < 4; ++m) {
                bf16x4 pw;
#pragma unroll
                for (int r = 0; r < 4; ++r) {
                    const float p = __expf(sf[qn][m][r]);
                    rs += p;
                    pw[r] = f2bf(p);
                }
                *(bf16x4*)&pb[(qn * 16 + l16) * 72 + m * 16 + quad * 4] = pw;
            }
            li[qn] += rs;
        }
        bf16x8 pf[2][2];
#pragma unroll
        for (int qn = 0; qn < 2; ++qn)
#pragma unroll
            for (int ks = 0; ks < 2; ++ks)
                pf[qn][ks] = *(const bf16x8*)&pb[(qn * 16 + l16) * 72 + ks * 32 + quad * 8];
#pragma unroll
        for (int nc = 0; nc < 4; ++nc) {
            const bf16x8 vf0 = *(const bf16x8*)&VB_[0][(nc * 16 + l16) * 32 + quad * 8];
            const bf16x8 vf1 = *(const bf16x8*)&VB_[1][(nc * 16 + l16) * 32 + quad * 8];
#pragma unroll
            for (int qn = 0; qn < 2; ++qn) {
                accO[qn][nc] = __builtin_amdgcn_mfma_f32_16x16x32_bf16(vf0, pf[qn][0],
                                                                      accO[qn][nc], 0, 0, 0);
                accO[qn][nc] = __builtin_amdgcn_mfma_f32_16x16x32_bf16(vf1, pf[qn][1],
                                                                      accO[qn][nc], 0, 0, 0);
            }
        }
    };

    stage(0, kA, vA);
    __syncthreads();
    for (int t = 0; t < ntiles; t += 2) {
        stage(t + 1, kB, vB);
        tile_step(kA, vA, t);
        __syncthreads();
        if (t + 2 < ntiles) stage(t + 2, kA, vA);
        tile_step(kB, vB, t + 1);
        __syncthreads();
    }

#pragma unroll
    for (int qn = 0; qn < 2; ++qn) {
        li[qn] += __shfl_xor(li[qn], 16, 64);
        li[qn] += __shfl_xor(li[qn], 32, 64);
        const float inv = 1.0f / li[qn];
        const int npos = qbase + qn * 16 + l16;
#pragma unroll
        for (int nc = 0; nc < 4; ++nc) {
            bf16x4 ow;
#pragma unroll
            for (int r = 0; r < 4; ++r) ow[r] = f2bf(accO[qn][nc][r] * inv);
            *(bf16x4*)&og[(size_t)(bb * 2048 + npos) * 1024 + hh * 64 + nc * 16 + quad * 4] = ow;
        }
    }
}

// ---------------------------------------------------------------------------
// Launch  (4 dispatches: prep, gemm<0>, attn, gemm<1>)
// ---------------------------------------------------------------------------
extern "C" void kernel_launch(void* const* d_in, const int* in_sizes, int n_in,
                              void* d_out, int out_size, void* d_ws, size_t ws_size,
                              hipStream_t stream) {
    const float* x     = (const float*)d_in[0];
    const float* gamma = (const float*)d_in[1];
    const float* w_qkv = (const float*)d_in[2];
    const float* w_out = (const float*)d_in[3];
    float* out = (float*)d_out;
    char* ws = (char*)d_ws;

    short* xn     = (short*)(ws);                    //  8 MB
    short* wqkvT  = (short*)(ws + 8388608);          //  6 MB
    short* woutT  = (short*)(ws + 14680064);         //  2 MB
    short* q      = (short*)(ws + 16777216);         //  8 MB: [32][2048][64]
    short* k      = q + 32 * 2048 * 64;              //  8 MB: [32][2048][64]
    short* vt     = k + 32 * 2048 * 64;              //  8 MB: [32][64][2048] (written by gemm<0>)
    short* attn   = (short*)(ws + 41943040);         //  8 MB

    // prep: 768 (wqkv T) + 256 (wout T) + 4096 (rmsnorm) = 5120 blocks
    prep_kernel<<<5120, 256, 0, stream>>>(x, gamma, w_qkv, w_out, xn, wqkvT, woutT);
    // 128x128 tile, BK=32: 24x32 = 768 blocks (3/CU)
    gemm_bt<0, 4, 4, 2, 2><<<dim3(NQKV / 128, ROWS / 128), 256, 0, stream>>>(xn, wqkvT, q, vt,
                                                                             DIM, NQKV);
    // 512 blocks: (bh, 128-query tile), heavy qt first; 4 waves query-split
    attn_kernel<<<512, 256, 0, stream>>>(q, k, vt, attn);
    // 128x64 tile direct fp32: 16x32 = 512 blocks (2/CU)
    gemm_bt<1, 2, 4, 4, 1><<<dim3(DIM / 64, ROWS / 128), 256, 0, stream>>>(attn, woutT, out,
                                                                           nullptr, DIM, DIM);
}